// Round 12
// baseline (358.819 us; speedup 1.0000x reference)
//
#include <hip/hip_runtime.h>
#include <hip/hip_bf16.h>

typedef unsigned short u16;
typedef unsigned int u32;
typedef __attribute__((ext_vector_type(8))) short short8;    // 8 bf16 MFMA A/B frag
typedef __attribute__((ext_vector_type(4))) float f32x4;

#define KS1 1.44269504f   // log2(e)
#define KS2 2.88539008f   // 2*log2(e)

__device__ __forceinline__ float bf2f(u16 u) {
    union { u32 i; float f; } v; v.i = ((u32)u) << 16; return v.f;
}
__device__ __forceinline__ u16 f2bf(float f) {            // RNE
    union { float f; u32 i; } v; v.f = f;
    u32 r = v.i + 0x7fffu + ((v.i >> 16) & 1u);
    return (u16)(r >> 16);
}
// pack two f32 -> two bf16 (truncation) in ONE v_perm (h state only)
__device__ __forceinline__ u32 pack_bf2(float lo, float hi) {
    return __builtin_amdgcn_perm(__float_as_uint(hi), __float_as_uint(lo), 0x07060302u);
}
// relu + RNE pack (epilogue intermediates)
__device__ __forceinline__ u32 pack_relu(float a, float b) {
    return (u32)f2bf(fmaxf(a, 0.f)) | ((u32)f2bf(fmaxf(b, 0.f)) << 16);
}
__device__ __forceinline__ f32x4 bias4(const u16* b) {
    uint2 u = *(const uint2*)b;
    f32x4 r;
    r[0] = bf2f((u16)(u.x & 0xffffu)); r[1] = bf2f((u16)(u.x >> 16));
    r[2] = bf2f((u16)(u.y & 0xffffu)); r[3] = bf2f((u16)(u.y >> 16));
    return r;
}
// SOFT BARRIER: LDS-only drain + barrier. Unlike __syncthreads() (which the
// compiler lowers to s_waitcnt vmcnt(0) lgkmcnt(0); s_barrier), this leaves
// global loads IN FLIGHT across the barrier — the per-step xp-gather prefetch
// keeps its latency hiding. Correctness: barrier only protects LDS exchange
// (lgkmcnt(0) retires our ds_writes); consumed global loads get per-load
// dependence s_waitcnt vmcnt(N) from the compiler.
__device__ __forceinline__ void soft_barrier() {
    __asm__ __volatile__("s_waitcnt lgkmcnt(0)\n\ts_barrier" ::: "memory");
}
// XOR-swizzled exchange buffer (proven bank-free: <=2-way).
__device__ __forceinline__ void xwrite(u16* buf, int D2, int row, int quad, int jt, u32 w0, u32 w1) {
    int ch = jt * 2 + (quad >> 1);
    *(uint2*)(buf + row * D2 + ((ch ^ (row & 7)) << 3) + ((quad & 1) << 2)) = (uint2){w0, w1};
}
__device__ __forceinline__ short8 xread(const u16* buf, int D2, int row, int quad, int kc) {
    return *(const short8*)(buf + row * D2 + (((kc * 4 + quad) ^ (row & 7)) << 3));
}
#define MFMA16 __builtin_amdgcn_mfma_f32_16x16x32_bf16

// ---------------------------------------------------------------------------
// k_pre (391 blocks): each block does 2 GEMM row-tiles (xp1) + grid-stride
// edge cast; blocks 0..3 additionally emit the scaled weight copies.
// ---------------------------------------------------------------------------
__global__ __launch_bounds__(256) void k_pre(
    const u16* __restrict__ X, const u16* __restrict__ pw, const u16* __restrict__ pb,
    u16* __restrict__ XP, int M,
    const int* __restrict__ e, float* __restrict__ eout, int n4,
    const u16* __restrict__ w1i, const u16* __restrict__ w1h,
    const u16* __restrict__ w2i, const u16* __restrict__ w2h,
    u16* __restrict__ wss)
{
    const int bid  = blockIdx.x;
    const int tid  = threadIdx.x;
    const int lane = tid & 63;
    const int wave = tid >> 6;
    const int col  = lane & 15;
    const int quad = lane >> 4;

    // ---- xp1 GEMM: two row-tiles per block ----
#pragma unroll 1
    for (int rep = 0; rep < 2; ++rep) {
        const int row0 = ((bid * 2 + rep) * 4 + wave) * 16;
        if (row0 >= M) break;
        f32x4 c1[4];
#pragma unroll
        for (int jt = 0; jt < 4; ++jt) c1[jt] = (f32x4){0.f, 0.f, 0.f, 0.f};
        {
            const u16* xrow = X  + (size_t)(row0 + col) * 64 + quad * 8;
            const u16* wrow = pw + (size_t)col * 64 + quad * 8;
#pragma unroll
            for (int kc = 0; kc < 64; kc += 32) {
                short8 a = *(const short8*)(xrow + kc);
#pragma unroll
                for (int jt = 0; jt < 4; ++jt) {
                    short8 b = *(const short8*)(wrow + (size_t)jt * 16 * 64 + kc);
                    c1[jt] = MFMA16(a, b, c1[jt], 0, 0, 0);
                }
            }
        }
#pragma unroll
        for (int jt = 0; jt < 4; ++jt) {
            float bias = bf2f(pb[jt * 16 + col]);
#pragma unroll
            for (int r = 0; r < 4; ++r) {
                float v = fmaxf(c1[jt][r] + bias, 0.f);
                XP[(size_t)(row0 + quad * 4 + r) * 64 + jt * 16 + col] = f2bf(v);
            }
        }
    }

    // ---- edge cast, grid-stride ----
    for (int i = bid * 256 + tid; i < n4; i += (int)gridDim.x * 256) {
        int4 v = *(const int4*)(e + (size_t)i * 4);
        float4 o;
        o.x = (float)v.x; o.y = (float)v.y; o.z = (float)v.z; o.w = (float)v.w;
        *(float4*)(eout + (size_t)i * 4) = o;
    }

    // ---- scaled weight copies (blocks 0..3) ----
    if (bid < 4) {
        const u16* Wsrc = (bid == 0) ? w1i : (bid == 1) ? w1h : (bid == 2) ? w2i : w2h;
        u16* Wdst = wss + (size_t)bid * 16384;
        for (int idx = tid; idx < 16384; idx += 256) {
            int row = idx >> 6;
            float sc = (row >= 128 && row < 192) ? KS2 : KS1;
            Wdst[idx] = f2bf(bf2f(Wsrc[idx]) * sc);
        }
    }
}

// ===========================================================================
// LSTM v7 = v6 with soft barriers (lgkm-only drain) in the hot path so the
// per-step xp-gather prefetch stays in flight across the h-exchange barrier.
// ===========================================================================

#define NONLIN(ACC, CST, HW0, HW1)                                             \
    {                                                                          \
        float hv[4];                                                           \
        _Pragma("unroll") for (int r = 0; r < 4; ++r) {                        \
            float iv = ACC[0][r], fv = ACC[1][r], gv = ACC[2][r], ov = ACC[3][r]; \
            float e_i = __builtin_amdgcn_exp2f(-iv);                           \
            float e_f = __builtin_amdgcn_exp2f(-fv);                           \
            float e_g = __builtin_amdgcn_exp2f(gv);                            \
            float sf  = __builtin_amdgcn_rcpf(1.0f + e_f);                     \
            float rig = __builtin_amdgcn_rcpf((1.0f + e_i) * (1.0f + e_g));    \
            float tt  = __builtin_fmaf(e_g, KS2, -KS2);                        \
            float cn  = __builtin_fmaf(sf, CST[r], tt * rig);                  \
            CST[r] = cn;                                                       \
            float e_c = __builtin_amdgcn_exp2f(cn);                            \
            float e_o = __builtin_amdgcn_exp2f(-ov);                           \
            float roc = __builtin_amdgcn_rcpf((1.0f + e_o) * (1.0f + e_c));    \
            hv[r] = (e_c - 1.0f) * roc;                                        \
        }                                                                      \
        HW0 = pack_bf2(hv[0], hv[1]);                                          \
        HW1 = pack_bf2(hv[2], hv[3]);                                          \
    }

// one-time per-block setup: thread ids, scaled bias -> LDS, weight frags
#define LSTM_SETUP                                                             \
    const int tid  = threadIdx.x;                                              \
    const int lane = tid & 63;                                                 \
    const int w    = tid >> 6;                                                 \
    const int col  = lane & 15;                                                \
    const int quad = lane >> 4;                                                \
    {                                                                          \
        int j = tid;                                                           \
        float sc = (j >= 128 && j < 192) ? KS2 : KS1;                          \
        lds_b[j] = (bf2f(bih[j]) + bf2f(bhh[j])) * sc;                         \
    }                                                                          \
    short8 wf[8], hf[8];                                                       \
    _Pragma("unroll") for (int g = 0; g < 4; ++g) {                            \
        int jt = w + 4 * g;                                                    \
        const u16* wi = wihs + (size_t)(jt * 16 + col) * 64 + quad * 8;        \
        const u16* wh = whhs + (size_t)(jt * 16 + col) * 64 + quad * 8;        \
        wf[g * 2 + 0] = *(const short8*)(wi);                                  \
        wf[g * 2 + 1] = *(const short8*)(wi + 32);                             \
        hf[g * 2 + 0] = *(const short8*)(wh);                                  \
        hf[g * 2 + 1] = *(const short8*)(wh + 32);                             \
    }

// per-group state + prefetch (node0/actB/nodeA/nodeB defined by caller)
#define LSTM_GROUP_INIT                                                        \
    int4 sidxA = *(const int4*)(src + (size_t)nodeA * 16 + quad * 4);          \
    int4 sidxB = *(const int4*)(src + (size_t)nodeB * 16 + quad * 4);          \
    short8 xbA0, xbA1, xbB0, xbB1;                                             \
    {                                                                          \
        int sA = __shfl(sidxA.x, col, 64);                                     \
        const u16* pA = xp + (size_t)sA * 64 + quad * 8;                       \
        xbA0 = *(const short8*)pA; xbA1 = *(const short8*)(pA + 32);           \
        int sB = __shfl(sidxB.x, col, 64);                                     \
        const u16* pB = xp + (size_t)sB * 64 + quad * 8;                       \
        xbB0 = *(const short8*)pB; xbB1 = *(const short8*)(pB + 32);           \
    }

#define LSTM2_CORE_LOOP                                                        \
    short8 hbA0 = (short8){0,0,0,0,0,0,0,0};                                   \
    short8 hbA1 = hbA0, hbB0 = hbA0, hbB1 = hbA0;                              \
    float cA[4], cB[4];                                                        \
    _Pragma("unroll") for (int i = 0; i < 4; ++i) { cA[i] = 0.f; cB[i] = 0.f; }\
    soft_barrier();                                                            \
    _Pragma("unroll 1") for (int t = 0; t < 16; ++t) {                         \
        f32x4 accA[4], accB[4];                                                \
        _Pragma("unroll") for (int g = 0; g < 4; ++g) {                        \
            f32x4 bc = *(const f32x4*)(lds_b + (w + 4 * g) * 16 + quad * 4);   \
            accA[g] = MFMA16(wf[g * 2 + 0], xbA0, bc, 0, 0, 0);                \
            accB[g] = MFMA16(wf[g * 2 + 0], xbB0, bc, 0, 0, 0);                \
            accA[g] = MFMA16(wf[g * 2 + 1], xbA1, accA[g], 0, 0, 0);           \
            accB[g] = MFMA16(wf[g * 2 + 1], xbB1, accB[g], 0, 0, 0);           \
        }                                                                      \
        if (t < 15) {                                                          \
            int tn = t + 1;                                                    \
            int cvA = (tn & 2) ? ((tn & 1) ? sidxA.w : sidxA.z)                \
                               : ((tn & 1) ? sidxA.y : sidxA.x);               \
            int snA = __shfl(cvA, ((tn >> 2) << 4) + col, 64);                 \
            const u16* pA = xp + (size_t)snA * 64 + quad * 8;                  \
            xbA0 = *(const short8*)pA; xbA1 = *(const short8*)(pA + 32);       \
            int cvB = (tn & 2) ? ((tn & 1) ? sidxB.w : sidxB.z)                \
                               : ((tn & 1) ? sidxB.y : sidxB.x);               \
            int snB = __shfl(cvB, ((tn >> 2) << 4) + col, 64);                 \
            const u16* pB = xp + (size_t)snB * 64 + quad * 8;                  \
            xbB0 = *(const short8*)pB; xbB1 = *(const short8*)(pB + 32);       \
        }                                                                      \
        if (t > 0) {                                                           \
            _Pragma("unroll") for (int g = 0; g < 4; ++g) {                    \
                accA[g] = MFMA16(hf[g * 2 + 0], hbA0, accA[g], 0, 0, 0);       \
                accB[g] = MFMA16(hf[g * 2 + 0], hbB0, accB[g], 0, 0, 0);       \
                accA[g] = MFMA16(hf[g * 2 + 1], hbA1, accA[g], 0, 0, 0);       \
                accB[g] = MFMA16(hf[g * 2 + 1], hbB1, accB[g], 0, 0, 0);       \
            }                                                                  \
        }                                                                      \
        u32 hwA0, hwA1, hwB0, hwB1;                                            \
        NONLIN(accA, cA, hwA0, hwA1)                                           \
        NONLIN(accB, cB, hwB0, hwB1)                                           \
        u16* hbuf = lds_h[t & 1];                                              \
        xwrite(hbuf, 64, col,      quad, w, hwA0, hwA1);                       \
        xwrite(hbuf, 64, col + 16, quad, w, hwB0, hwB1);                       \
        soft_barrier();                                                        \
        hbA0 = xread(hbuf, 64, col,      quad, 0);                             \
        hbA1 = xread(hbuf, 64, col,      quad, 1);                             \
        hbB0 = xread(hbuf, 64, col + 16, quad, 0);                             \
        hbB1 = xread(hbuf, 64, col + 16, quad, 1);                             \
    }

// ---------------------------------------------------------------------------
// lstm_mid: layer-1 LSTM + fused Y1 + xp2; 2 groups (64 nodes) per block
// ---------------------------------------------------------------------------
__global__ __launch_bounds__(256) void lstm_mid(
    const u16* __restrict__ xp, const int* __restrict__ src,
    const u16* __restrict__ wihs, const u16* __restrict__ whhs,
    const u16* __restrict__ bih, const u16* __restrict__ bhh,
    const u16* __restrict__ X,
    const u16* __restrict__ llw, const u16* __restrict__ llb,
    const u16* __restrict__ lrw,
    const u16* __restrict__ pw, const u16* __restrict__ pb,
    u16* __restrict__ Y1, u16* __restrict__ XP2, int N)
{
    __shared__ float lds_b[256];        // 1KB scaled bias'
    __shared__ u16 lds_h[2][32 * 64];   // 8KB h double buffer
    __shared__ u16 bufY[32 * 64];       // 4KB Y1 exchange

    LSTM_SETUP

#pragma unroll 1
    for (int rep = 0; rep < 2; ++rep) {
        const int node0 = (blockIdx.x * 2 + rep) * 32;
        if (node0 >= N) break;                      // block-uniform
        const bool actB = (node0 + 32 <= N);
        const int nodeA = node0 + col;
        const int nodeB = actB ? (node0 + 16 + col) : nodeA;

        LSTM_GROUP_INIT
        LSTM2_CORE_LOOP

        // ---- epilogue: hb* = H B-frags for both groups ----
        {
            const u16* wr  = llw + (size_t)(w * 16 + col) * 64 + quad * 8;
            short8 ll0 = *(const short8*)wr, ll1 = *(const short8*)(wr + 32);
            const u16* wr2 = lrw + (size_t)(w * 16 + col) * 64 + quad * 8;
            short8 lr0 = *(const short8*)wr2, lr1 = *(const short8*)(wr2 + 32);
            f32x4 bY = bias4(llb + w * 16 + quad * 4);

            const u16* xrA = X + (size_t)nodeA * 64 + quad * 8;
            short8 rxA0 = *(const short8*)xrA, rxA1 = *(const short8*)(xrA + 32);
            const u16* xrB = X + (size_t)nodeB * 64 + quad * 8;
            short8 rxB0 = *(const short8*)xrB, rxB1 = *(const short8*)(xrB + 32);

            f32x4 aA = MFMA16(ll0, hbA0, bY, 0, 0, 0);
            aA = MFMA16(ll1, hbA1, aA, 0, 0, 0);
            aA = MFMA16(lr0, rxA0, aA, 0, 0, 0);
            aA = MFMA16(lr1, rxA1, aA, 0, 0, 0);
            f32x4 aB = MFMA16(ll0, hbB0, bY, 0, 0, 0);
            aB = MFMA16(ll1, hbB1, aB, 0, 0, 0);
            aB = MFMA16(lr0, rxB0, aB, 0, 0, 0);
            aB = MFMA16(lr1, rxB1, aB, 0, 0, 0);

            u32 yA0 = pack_relu(aA[0], aA[1]), yA1 = pack_relu(aA[2], aA[3]);
            u32 yB0 = pack_relu(aB[0], aB[1]), yB1 = pack_relu(aB[2], aB[3]);
            *(uint2*)(Y1 + (size_t)nodeA * 64 + w * 16 + quad * 4) = (uint2){yA0, yA1};
            if (actB) *(uint2*)(Y1 + (size_t)nodeB * 64 + w * 16 + quad * 4) = (uint2){yB0, yB1};
            xwrite(bufY, 64, col,      quad, w, yA0, yA1);
            xwrite(bufY, 64, col + 16, quad, w, yB0, yB1);
            soft_barrier();

            const u16* wp = pw + (size_t)(w * 16 + col) * 64 + quad * 8;
            short8 p0 = *(const short8*)wp, p1 = *(const short8*)(wp + 32);
            f32x4 bp = bias4(pb + w * 16 + quad * 4);

            short8 ybA0 = xread(bufY, 64, col,      quad, 0);
            short8 ybA1 = xread(bufY, 64, col,      quad, 1);
            short8 ybB0 = xread(bufY, 64, col + 16, quad, 0);
            short8 ybB1 = xread(bufY, 64, col + 16, quad, 1);

            f32x4 a2A = MFMA16(p0, ybA0, bp, 0, 0, 0);
            a2A = MFMA16(p1, ybA1, a2A, 0, 0, 0);
            f32x4 a2B = MFMA16(p0, ybB0, bp, 0, 0, 0);
            a2B = MFMA16(p1, ybB1, a2B, 0, 0, 0);

            *(uint2*)(XP2 + (size_t)nodeA * 64 + w * 16 + quad * 4) =
                (uint2){pack_relu(a2A[0], a2A[1]), pack_relu(a2A[2], a2A[3])};
            if (actB) *(uint2*)(XP2 + (size_t)nodeB * 64 + w * 16 + quad * 4) =
                (uint2){pack_relu(a2B[0], a2B[1]), pack_relu(a2B[2], a2B[3])};
            soft_barrier();   // bufY reuse guard for next rep
        }
    }
}

// ---------------------------------------------------------------------------
// lstm_post: layer-2 LSTM + fused Y2[128]->T1[192]->T2[64]->out[64] f32;
// 2 groups (64 nodes) per block
// ---------------------------------------------------------------------------
__global__ __launch_bounds__(256) void lstm_post(
    const u16* __restrict__ xp, const int* __restrict__ src,
    const u16* __restrict__ wihs, const u16* __restrict__ whhs,
    const u16* __restrict__ bih, const u16* __restrict__ bhh,
    const u16* __restrict__ Y1,
    const u16* __restrict__ llw2, const u16* __restrict__ llb2,
    const u16* __restrict__ lrw2,
    const u16* __restrict__ w1m, const u16* __restrict__ b1m,
    const u16* __restrict__ w2m, const u16* __restrict__ b2m,
    const u16* __restrict__ w3m, const u16* __restrict__ b3m,
    float* __restrict__ outp, int N)
{
    __shared__ float lds_b[256];        // 1KB
    __shared__ u16 lds_h[2][32 * 64];   // 8KB
    __shared__ u16 bufA[32 * 128];      // 8KB Y2 exchange (reused for T2 @ 64)
    __shared__ u16 bufB[32 * 192];      // 12KB T1 exchange

    LSTM_SETUP

#pragma unroll 1
    for (int rep = 0; rep < 2; ++rep) {
        const int node0 = (blockIdx.x * 2 + rep) * 32;
        if (node0 >= N) break;
        const bool actB = (node0 + 32 <= N);
        const int nodeA = node0 + col;
        const int nodeB = actB ? (node0 + 16 + col) : nodeA;

        LSTM_GROUP_INIT
        LSTM2_CORE_LOOP

        // ---- epilogue ----
        {
            const u16* yrA = Y1 + (size_t)nodeA * 64 + quad * 8;
            short8 ryA0 = *(const short8*)yrA, ryA1 = *(const short8*)(yrA + 32);
            const u16* yrB = Y1 + (size_t)nodeB * 64 + quad * 8;
            short8 ryB0 = *(const short8*)yrB, ryB1 = *(const short8*)(yrB + 32);

            // Y2 tiles jt = 2w, 2w+1
#pragma unroll
            for (int ti = 0; ti < 2; ++ti) {
                int jt = 2 * w + ti;
                const u16* wr = llw2 + (size_t)(jt * 16 + col) * 64 + quad * 8;
                short8 l0 = *(const short8*)wr, l1 = *(const short8*)(wr + 32);
                const u16* wr2 = lrw2 + (size_t)(jt * 16 + col) * 64 + quad * 8;
                short8 r0 = *(const short8*)wr2, r1 = *(const short8*)(wr2 + 32);
                f32x4 b0 = bias4(llb2 + jt * 16 + quad * 4);
                f32x4 aA = MFMA16(l0, hbA0, b0, 0, 0, 0);
                aA = MFMA16(l1, hbA1, aA, 0, 0, 0);
                aA = MFMA16(r0, ryA0, aA, 0, 0, 0);
                aA = MFMA16(r1, ryA1, aA, 0, 0, 0);
                xwrite(bufA, 128, col, quad, jt, pack_relu(aA[0], aA[1]), pack_relu(aA[2], aA[3]));
                f32x4 aB = MFMA16(l0, hbB0, b0, 0, 0, 0);
                aB = MFMA16(l1, hbB1, aB, 0, 0, 0);
                aB = MFMA16(r0, ryB0, aB, 0, 0, 0);
                aB = MFMA16(r1, ryB1, aB, 0, 0, 0);
                xwrite(bufA, 128, col + 16, quad, jt, pack_relu(aB[0], aB[1]), pack_relu(aB[2], aB[3]));
            }
            soft_barrier();

            short8 y2A[4], y2B[4];
#pragma unroll
            for (int kc = 0; kc < 4; ++kc) {
                y2A[kc] = xread(bufA, 128, col,      quad, kc);
                y2B[kc] = xread(bufA, 128, col + 16, quad, kc);
            }
            // T1 tiles jt = 3w..3w+2, K=128
#pragma unroll
            for (int ti = 0; ti < 3; ++ti) {
                int jt = 3 * w + ti;
                const u16* wr = w1m + (size_t)(jt * 16 + col) * 128 + quad * 8;
                short8 wk[4];
#pragma unroll
                for (int kc = 0; kc < 4; ++kc) wk[kc] = *(const short8*)(wr + kc * 32);
                f32x4 b1v = bias4(b1m + jt * 16 + quad * 4);
                f32x4 aA = b1v, aB = b1v;
#pragma unroll
                for (int kc = 0; kc < 4; ++kc) {
                    aA = MFMA16(wk[kc], y2A[kc], aA, 0, 0, 0);
                    aB = MFMA16(wk[kc], y2B[kc], aB, 0, 0, 0);
                }
                xwrite(bufB, 192, col,      quad, jt, pack_relu(aA[0], aA[1]), pack_relu(aA[2], aA[3]));
                xwrite(bufB, 192, col + 16, quad, jt, pack_relu(aB[0], aB[1]), pack_relu(aB[2], aB[3]));
            }
            soft_barrier();

            short8 t1A[6], t1B[6];
#pragma unroll
            for (int kc = 0; kc < 6; ++kc) {
                t1A[kc] = xread(bufB, 192, col,      quad, kc);
                t1B[kc] = xread(bufB, 192, col + 16, quad, kc);
            }
            // T2 tile jt=w, K=192 (bufA reuse @ stride 64 — Y2 reads drained at T1 barrier)
            {
                const u16* wr = w2m + (size_t)(w * 16 + col) * 192 + quad * 8;
                f32x4 b2v = bias4(b2m + w * 16 + quad * 4);
                f32x4 aA = b2v, aB = b2v;
#pragma unroll
                for (int kc = 0; kc < 6; ++kc) {
                    short8 wk = *(const short8*)(wr + kc * 32);
                    aA = MFMA16(wk, t1A[kc], aA, 0, 0, 0);
                    aB = MFMA16(wk, t1B[kc], aB, 0, 0, 0);
                }
                xwrite(bufA, 64, col,      quad, w, pack_relu(aA[0], aA[1]), pack_relu(aA[2], aA[3]));
                xwrite(bufA, 64, col + 16, quad, w, pack_relu(aB[0], aB[1]), pack_relu(aB[2], aB[3]));
            }
            soft_barrier();

            short8 t2A0 = xread(bufA, 64, col,      quad, 0);
            short8 t2A1 = xread(bufA, 64, col,      quad, 1);
            short8 t2B0 = xread(bufA, 64, col + 16, quad, 0);
            short8 t2B1 = xread(bufA, 64, col + 16, quad, 1);
            // out tile jt=w, K=64, f32 store
            {
                const u16* wr = w3m + (size_t)(w * 16 + col) * 64 + quad * 8;
                short8 l0 = *(const short8*)wr, l1 = *(const short8*)(wr + 32);
                f32x4 b3v = bias4(b3m + w * 16 + quad * 4);
                f32x4 aA = MFMA16(l0, t2A0, b3v, 0, 0, 0);
                aA = MFMA16(l1, t2A1, aA, 0, 0, 0);
                f32x4 aB = MFMA16(l0, t2B0, b3v, 0, 0, 0);
                aB = MFMA16(l1, t2B1, aB, 0, 0, 0);
                float4 oA;
                oA.x = fmaxf(aA[0], 0.f); oA.y = fmaxf(aA[1], 0.f);
                oA.z = fmaxf(aA[2], 0.f); oA.w = fmaxf(aA[3], 0.f);
                *(float4*)(outp + (size_t)nodeA * 64 + w * 16 + quad * 4) = oA;
                if (actB) {
                    float4 oB;
                    oB.x = fmaxf(aB[0], 0.f); oB.y = fmaxf(aB[1], 0.f);
                    oB.z = fmaxf(aB[2], 0.f); oB.w = fmaxf(aB[3], 0.f);
                    *(float4*)(outp + (size_t)nodeB * 64 + w * 16 + quad * 4) = oB;
                }
            }
            soft_barrier();   // buf reuse guard for next rep
        }
    }
}

// ---------------------------------------------------------------------------
extern "C" void kernel_launch(void* const* d_in, const int* in_sizes, int n_in,
                              void* d_out, int out_size, void* d_ws, size_t ws_size,
                              hipStream_t stream)
{
    const u16* x       = (const u16*)d_in[0];
    const int* edge    = (const int*)d_in[1];
    const u16* p1_pw   = (const u16*)d_in[3];
    const u16* p1_pb   = (const u16*)d_in[4];
    const u16* p1_wih  = (const u16*)d_in[5];
    const u16* p1_whh  = (const u16*)d_in[6];
    const u16* p1_bih  = (const u16*)d_in[7];
    const u16* p1_bhh  = (const u16*)d_in[8];
    const u16* p1_llw  = (const u16*)d_in[9];
    const u16* p1_llb  = (const u16*)d_in[10];
    const u16* p1_lrw  = (const u16*)d_in[11];
    const u16* p2_pw   = (const u16*)d_in[12];
    const u16* p2_pb   = (const u16*)d_in[13];
    const u16* p2_wih  = (const u16*)d_in[14];
    const u16* p2_whh  = (const u16*)d_in[15];
    const u16* p2_bih  = (const u16*)d_in[16];
    const u16* p2_bhh  = (const u16*)d_in[17];
    const u16* p2_llw  = (const u16*)d_in[18];
    const u16* p2_llb  = (const u16*)d_in[19];
    const u16* p2_lrw  = (const u16*)d_in[20];
    const u16* lin1w   = (const u16*)d_in[21];
    const u16* lin1b   = (const u16*)d_in[22];
    const u16* lin2w   = (const u16*)d_in[23];
    const u16* lin2b   = (const u16*)d_in[24];
    const u16* lin3w   = (const u16*)d_in[25];
    const u16* lin3b   = (const u16*)d_in[26];
    (void)n_in; (void)ws_size;

    const int N  = in_sizes[0] / 64;     // 50000
    const int E2 = in_sizes[1];          // 1600000
    const int* srcIdx = edge;

    // workspace: scaled weights 128KB @0; xp1 @1MB; xp2 @8MB; Y1 @15MB
    char* w = (char*)d_ws;
    u16* wss   = (u16*)(w);
    u16* xp1   = (u16*)(w + 1u  * 1024 * 1024);
    u16* xp2   = (u16*)(w + 8u  * 1024 * 1024);
    u16* bufY1 = (u16*)(w + 15u * 1024 * 1024);
    u16* wih1s = wss;
    u16* whh1s = wss + 16384;
    u16* wih2s = wss + 32768;
    u16* whh2s = wss + 49152;

    float* out_h    = (float*)d_out;
    float* out_edge = (float*)d_out + (size_t)N * 64;
    (void)out_size;

    const int tiles = (N + 63) / 64;          // 782 GEMM row-tiles
    const int gpre  = (tiles + 1) / 2;        // 391 k_pre blocks
    const int gbl   = (N + 63) / 64;          // 782 lstm blocks (64 nodes each)
    const int n4    = E2 / 4;

    dim3 block(256);

    hipLaunchKernelGGL(k_pre, dim3(gpre), block, 0, stream,
                       x, p1_pw, p1_pb, xp1, N,
                       edge, out_edge, n4,
                       p1_wih, p1_whh, p2_wih, p2_whh, wss);
    hipLaunchKernelGGL(lstm_mid, dim3(gbl), block, 0, stream,
                       xp1, srcIdx, wih1s, whh1s, p1_bih, p1_bhh,
                       x, p1_llw, p1_llb, p1_lrw, p2_pw, p2_pb, bufY1, xp2, N);
    hipLaunchKernelGGL(lstm_post, dim3(gbl), block, 0, stream,
                       xp2, srcIdx, wih2s, whh2s, p2_bih, p2_bhh,
                       bufY1, p2_llw, p2_llb, p2_lrw,
                       lin1w, lin1b, lin2w, lin2b, lin3w, lin3b, out_h, N);
}

// Round 13
// 356.930 us; speedup vs baseline: 1.0053x; 1.0053x over previous
//
#include <hip/hip_runtime.h>
#include <hip/hip_bf16.h>

typedef unsigned short u16;
typedef unsigned int u32;
typedef __attribute__((ext_vector_type(8))) short short8;    // 8 bf16 MFMA A/B frag
typedef __attribute__((ext_vector_type(4))) float f32x4;

#define KS1 1.44269504f   // log2(e)
#define KS2 2.88539008f   // 2*log2(e)

__device__ __forceinline__ float bf2f(u16 u) {
    union { u32 i; float f; } v; v.i = ((u32)u) << 16; return v.f;
}
__device__ __forceinline__ u16 f2bf(float f) {            // RNE
    union { float f; u32 i; } v; v.f = f;
    u32 r = v.i + 0x7fffu + ((v.i >> 16) & 1u);
    return (u16)(r >> 16);
}
// pack two f32 -> two bf16 (truncation) in ONE v_perm (h state only)
__device__ __forceinline__ u32 pack_bf2(float lo, float hi) {
    return __builtin_amdgcn_perm(__float_as_uint(hi), __float_as_uint(lo), 0x07060302u);
}
// relu + RNE pack (epilogue intermediates)
__device__ __forceinline__ u32 pack_relu(float a, float b) {
    return (u32)f2bf(fmaxf(a, 0.f)) | ((u32)f2bf(fmaxf(b, 0.f)) << 16);
}
__device__ __forceinline__ f32x4 bias4(const u16* b) {
    uint2 u = *(const uint2*)b;
    f32x4 r;
    r[0] = bf2f((u16)(u.x & 0xffffu)); r[1] = bf2f((u16)(u.x >> 16));
    r[2] = bf2f((u16)(u.y & 0xffffu)); r[3] = bf2f((u16)(u.y >> 16));
    return r;
}
// soft barrier: LDS-only drain + barrier (global loads stay in flight)
__device__ __forceinline__ void soft_barrier() {
    __asm__ __volatile__("s_waitcnt lgkmcnt(0)\n\ts_barrier" ::: "memory");
}
// XOR-swizzled exchange buffer (proven bank-free: <=2-way).
__device__ __forceinline__ void xwrite(u16* buf, int D2, int row, int quad, int jt, u32 w0, u32 w1) {
    int ch = jt * 2 + (quad >> 1);
    *(uint2*)(buf + row * D2 + ((ch ^ (row & 7)) << 3) + ((quad & 1) << 2)) = (uint2){w0, w1};
}
__device__ __forceinline__ short8 xread(const u16* buf, int D2, int row, int quad, int kc) {
    return *(const short8*)(buf + row * D2 + (((kc * 4 + quad) ^ (row & 7)) << 3));
}
#define MFMA16 __builtin_amdgcn_mfma_f32_16x16x32_bf16

// ---------------------------------------------------------------------------
// k_pre (391 blocks): 2 GEMM row-tiles (xp1) + grid-stride edge cast;
// blocks 0..3 additionally emit the scaled weight copies.
// ---------------------------------------------------------------------------
__global__ __launch_bounds__(256) void k_pre(
    const u16* __restrict__ X, const u16* __restrict__ pw, const u16* __restrict__ pb,
    u16* __restrict__ XP, int M,
    const int* __restrict__ e, float* __restrict__ eout, int n4,
    const u16* __restrict__ w1i, const u16* __restrict__ w1h,
    const u16* __restrict__ w2i, const u16* __restrict__ w2h,
    u16* __restrict__ wss)
{
    const int bid  = blockIdx.x;
    const int tid  = threadIdx.x;
    const int lane = tid & 63;
    const int wave = tid >> 6;
    const int col  = lane & 15;
    const int quad = lane >> 4;

#pragma unroll 1
    for (int rep = 0; rep < 2; ++rep) {
        const int row0 = ((bid * 2 + rep) * 4 + wave) * 16;
        if (row0 >= M) break;
        f32x4 c1[4];
#pragma unroll
        for (int jt = 0; jt < 4; ++jt) c1[jt] = (f32x4){0.f, 0.f, 0.f, 0.f};
        {
            const u16* xrow = X  + (size_t)(row0 + col) * 64 + quad * 8;
            const u16* wrow = pw + (size_t)col * 64 + quad * 8;
#pragma unroll
            for (int kc = 0; kc < 64; kc += 32) {
                short8 a = *(const short8*)(xrow + kc);
#pragma unroll
                for (int jt = 0; jt < 4; ++jt) {
                    short8 b = *(const short8*)(wrow + (size_t)jt * 16 * 64 + kc);
                    c1[jt] = MFMA16(a, b, c1[jt], 0, 0, 0);
                }
            }
        }
#pragma unroll
        for (int jt = 0; jt < 4; ++jt) {
            float bias = bf2f(pb[jt * 16 + col]);
#pragma unroll
            for (int r = 0; r < 4; ++r) {
                float v = fmaxf(c1[jt][r] + bias, 0.f);
                XP[(size_t)(row0 + quad * 4 + r) * 64 + jt * 16 + col] = f2bf(v);
            }
        }
    }

    for (int i = bid * 256 + tid; i < n4; i += (int)gridDim.x * 256) {
        int4 v = *(const int4*)(e + (size_t)i * 4);
        float4 o;
        o.x = (float)v.x; o.y = (float)v.y; o.z = (float)v.z; o.w = (float)v.w;
        *(float4*)(eout + (size_t)i * 4) = o;
    }

    if (bid < 4) {
        const u16* Wsrc = (bid == 0) ? w1i : (bid == 1) ? w1h : (bid == 2) ? w2i : w2h;
        u16* Wdst = wss + (size_t)bid * 16384;
        for (int idx = tid; idx < 16384; idx += 256) {
            int row = idx >> 6;
            float sc = (row >= 128 && row < 192) ? KS2 : KS1;
            Wdst[idx] = f2bf(bf2f(Wsrc[idx]) * sc);
        }
    }
}

// ===========================================================================
// LSTM v8 = v7 with PREFETCH DEPTH 2 on the xp gather: t-loop manually
// unrolled by 2 with even/odd register sets; a set is reloaded for t+2 right
// after its MFMAs consume it -> gather stays in flight ~2 steps (covers L3
// latency; xp (6.4MB) exceeds the 4MB per-XCD L2, so gathers hit L3).
// ===========================================================================

#define NONLIN(ACC, CST, HW0, HW1)                                             \
    {                                                                          \
        float hv[4];                                                           \
        _Pragma("unroll") for (int r = 0; r < 4; ++r) {                        \
            float iv = ACC[0][r], fv = ACC[1][r], gv = ACC[2][r], ov = ACC[3][r]; \
            float e_i = __builtin_amdgcn_exp2f(-iv);                           \
            float e_f = __builtin_amdgcn_exp2f(-fv);                           \
            float e_g = __builtin_amdgcn_exp2f(gv);                            \
            float sf  = __builtin_amdgcn_rcpf(1.0f + e_f);                     \
            float rig = __builtin_amdgcn_rcpf((1.0f + e_i) * (1.0f + e_g));    \
            float tt  = __builtin_fmaf(e_g, KS2, -KS2);                        \
            float cn  = __builtin_fmaf(sf, CST[r], tt * rig);                  \
            CST[r] = cn;                                                       \
            float e_c = __builtin_amdgcn_exp2f(cn);                            \
            float e_o = __builtin_amdgcn_exp2f(-ov);                           \
            float roc = __builtin_amdgcn_rcpf((1.0f + e_o) * (1.0f + e_c));    \
            hv[r] = (e_c - 1.0f) * roc;                                        \
        }                                                                      \
        HW0 = pack_bf2(hv[0], hv[1]);                                          \
        HW1 = pack_bf2(hv[2], hv[3]);                                          \
    }

// gather xp row for step T of a stream into frag pair (X0,X1)
#define GATHER2(X0, X1, SIDX, T)                                               \
    {                                                                          \
        int cv_ = ((T) & 2) ? (((T) & 1) ? SIDX.w : SIDX.z)                    \
                            : (((T) & 1) ? SIDX.y : SIDX.x);                   \
        int sn_ = __shfl(cv_, (((T) >> 2) << 4) + col, 64);                    \
        const u16* p_ = xp + (size_t)sn_ * 64 + quad * 8;                      \
        X0 = *(const short8*)p_; X1 = *(const short8*)(p_ + 32);               \
    }

// one-time per-block setup
#define LSTM_SETUP                                                             \
    const int tid  = threadIdx.x;                                              \
    const int lane = tid & 63;                                                 \
    const int w    = tid >> 6;                                                 \
    const int col  = lane & 15;                                                \
    const int quad = lane >> 4;                                                \
    {                                                                          \
        int j = tid;                                                           \
        float sc = (j >= 128 && j < 192) ? KS2 : KS1;                          \
        lds_b[j] = (bf2f(bih[j]) + bf2f(bhh[j])) * sc;                         \
    }                                                                          \
    short8 wf[8], hf[8];                                                       \
    _Pragma("unroll") for (int g = 0; g < 4; ++g) {                            \
        int jt = w + 4 * g;                                                    \
        const u16* wi = wihs + (size_t)(jt * 16 + col) * 64 + quad * 8;        \
        const u16* wh = whhs + (size_t)(jt * 16 + col) * 64 + quad * 8;        \
        wf[g * 2 + 0] = *(const short8*)(wi);                                  \
        wf[g * 2 + 1] = *(const short8*)(wi + 32);                             \
        hf[g * 2 + 0] = *(const short8*)(wh);                                  \
        hf[g * 2 + 1] = *(const short8*)(wh + 32);                             \
    }

// per-group state + depth-2 prefetch (steps 0 and 1)
#define LSTM_GROUP_INIT                                                        \
    int4 sidxA = *(const int4*)(src + (size_t)nodeA * 16 + quad * 4);          \
    int4 sidxB = *(const int4*)(src + (size_t)nodeB * 16 + quad * 4);          \
    short8 xeA0, xeA1, xeB0, xeB1, xoA0, xoA1, xoB0, xoB1;                     \
    GATHER2(xeA0, xeA1, sidxA, 0)                                              \
    GATHER2(xeB0, xeB1, sidxB, 0)                                              \
    GATHER2(xoA0, xoA1, sidxA, 1)                                              \
    GATHER2(xoB0, xoB1, sidxB, 1)

// one LSTM step using frag set (XA0,XA1,XB0,XB1); reloads the set for T+2.
#define LSTM_STEP(T, HBUF, XA0, XA1, XB0, XB1)                                 \
    {                                                                          \
        f32x4 accA[4], accB[4];                                                \
        _Pragma("unroll") for (int g = 0; g < 4; ++g) {                        \
            f32x4 bc = *(const f32x4*)(lds_b + (w + 4 * g) * 16 + quad * 4);   \
            accA[g] = MFMA16(wf[g * 2 + 0], XA0, bc, 0, 0, 0);                 \
            accB[g] = MFMA16(wf[g * 2 + 0], XB0, bc, 0, 0, 0);                 \
            accA[g] = MFMA16(wf[g * 2 + 1], XA1, accA[g], 0, 0, 0);            \
            accB[g] = MFMA16(wf[g * 2 + 1], XB1, accB[g], 0, 0, 0);            \
        }                                                                      \
        if ((T) + 2 < 16) {                                                    \
            GATHER2(XA0, XA1, sidxA, (T) + 2)                                  \
            GATHER2(XB0, XB1, sidxB, (T) + 2)                                  \
        }                                                                      \
        if ((T) > 0) {                                                         \
            _Pragma("unroll") for (int g = 0; g < 4; ++g) {                    \
                accA[g] = MFMA16(hf[g * 2 + 0], hbA0, accA[g], 0, 0, 0);       \
                accB[g] = MFMA16(hf[g * 2 + 0], hbB0, accB[g], 0, 0, 0);       \
                accA[g] = MFMA16(hf[g * 2 + 1], hbA1, accA[g], 0, 0, 0);       \
                accB[g] = MFMA16(hf[g * 2 + 1], hbB1, accB[g], 0, 0, 0);       \
            }                                                                  \
        }                                                                      \
        u32 hwA0, hwA1, hwB0, hwB1;                                            \
        NONLIN(accA, cA, hwA0, hwA1)                                           \
        NONLIN(accB, cB, hwB0, hwB1)                                           \
        xwrite(HBUF, 64, col,      quad, w, hwA0, hwA1);                       \
        xwrite(HBUF, 64, col + 16, quad, w, hwB0, hwB1);                       \
        soft_barrier();                                                        \
        hbA0 = xread(HBUF, 64, col,      quad, 0);                             \
        hbA1 = xread(HBUF, 64, col,      quad, 1);                             \
        hbB0 = xread(HBUF, 64, col + 16, quad, 0);                             \
        hbB1 = xread(HBUF, 64, col + 16, quad, 1);                             \
    }

#define LSTM2_CORE_LOOP                                                        \
    short8 hbA0 = (short8){0,0,0,0,0,0,0,0};                                   \
    short8 hbA1 = hbA0, hbB0 = hbA0, hbB1 = hbA0;                              \
    float cA[4], cB[4];                                                        \
    _Pragma("unroll") for (int i = 0; i < 4; ++i) { cA[i] = 0.f; cB[i] = 0.f; }\
    soft_barrier();                                                            \
    _Pragma("unroll 1") for (int tt = 0; tt < 16; tt += 2) {                   \
        LSTM_STEP(tt,     lds_h[0], xeA0, xeA1, xeB0, xeB1)                    \
        LSTM_STEP(tt + 1, lds_h[1], xoA0, xoA1, xoB0, xoB1)                    \
    }

// ---------------------------------------------------------------------------
// lstm_mid: layer-1 LSTM + fused Y1 + xp2; 2 groups (64 nodes) per block
// ---------------------------------------------------------------------------
__global__ __launch_bounds__(256) void lstm_mid(
    const u16* __restrict__ xp, const int* __restrict__ src,
    const u16* __restrict__ wihs, const u16* __restrict__ whhs,
    const u16* __restrict__ bih, const u16* __restrict__ bhh,
    const u16* __restrict__ X,
    const u16* __restrict__ llw, const u16* __restrict__ llb,
    const u16* __restrict__ lrw,
    const u16* __restrict__ pw, const u16* __restrict__ pb,
    u16* __restrict__ Y1, u16* __restrict__ XP2, int N)
{
    __shared__ float lds_b[256];        // 1KB scaled bias'
    __shared__ u16 lds_h[2][32 * 64];   // 8KB h double buffer
    __shared__ u16 bufY[32 * 64];       // 4KB Y1 exchange

    LSTM_SETUP

#pragma unroll 1
    for (int rep = 0; rep < 2; ++rep) {
        const int node0 = (blockIdx.x * 2 + rep) * 32;
        if (node0 >= N) break;                      // block-uniform
        const bool actB = (node0 + 32 <= N);
        const int nodeA = node0 + col;
        const int nodeB = actB ? (node0 + 16 + col) : nodeA;

        LSTM_GROUP_INIT
        LSTM2_CORE_LOOP

        // ---- epilogue: hb* = H B-frags for both groups ----
        {
            const u16* wr  = llw + (size_t)(w * 16 + col) * 64 + quad * 8;
            short8 ll0 = *(const short8*)wr, ll1 = *(const short8*)(wr + 32);
            const u16* wr2 = lrw + (size_t)(w * 16 + col) * 64 + quad * 8;
            short8 lr0 = *(const short8*)wr2, lr1 = *(const short8*)(wr2 + 32);
            f32x4 bY = bias4(llb + w * 16 + quad * 4);

            const u16* xrA = X + (size_t)nodeA * 64 + quad * 8;
            short8 rxA0 = *(const short8*)xrA, rxA1 = *(const short8*)(xrA + 32);
            const u16* xrB = X + (size_t)nodeB * 64 + quad * 8;
            short8 rxB0 = *(const short8*)xrB, rxB1 = *(const short8*)(xrB + 32);

            f32x4 aA = MFMA16(ll0, hbA0, bY, 0, 0, 0);
            aA = MFMA16(ll1, hbA1, aA, 0, 0, 0);
            aA = MFMA16(lr0, rxA0, aA, 0, 0, 0);
            aA = MFMA16(lr1, rxA1, aA, 0, 0, 0);
            f32x4 aB = MFMA16(ll0, hbB0, bY, 0, 0, 0);
            aB = MFMA16(ll1, hbB1, aB, 0, 0, 0);
            aB = MFMA16(lr0, rxB0, aB, 0, 0, 0);
            aB = MFMA16(lr1, rxB1, aB, 0, 0, 0);

            u32 yA0 = pack_relu(aA[0], aA[1]), yA1 = pack_relu(aA[2], aA[3]);
            u32 yB0 = pack_relu(aB[0], aB[1]), yB1 = pack_relu(aB[2], aB[3]);
            *(uint2*)(Y1 + (size_t)nodeA * 64 + w * 16 + quad * 4) = (uint2){yA0, yA1};
            if (actB) *(uint2*)(Y1 + (size_t)nodeB * 64 + w * 16 + quad * 4) = (uint2){yB0, yB1};
            xwrite(bufY, 64, col,      quad, w, yA0, yA1);
            xwrite(bufY, 64, col + 16, quad, w, yB0, yB1);
            soft_barrier();

            const u16* wp = pw + (size_t)(w * 16 + col) * 64 + quad * 8;
            short8 p0 = *(const short8*)wp, p1 = *(const short8*)(wp + 32);
            f32x4 bp = bias4(pb + w * 16 + quad * 4);

            short8 ybA0 = xread(bufY, 64, col,      quad, 0);
            short8 ybA1 = xread(bufY, 64, col,      quad, 1);
            short8 ybB0 = xread(bufY, 64, col + 16, quad, 0);
            short8 ybB1 = xread(bufY, 64, col + 16, quad, 1);

            f32x4 a2A = MFMA16(p0, ybA0, bp, 0, 0, 0);
            a2A = MFMA16(p1, ybA1, a2A, 0, 0, 0);
            f32x4 a2B = MFMA16(p0, ybB0, bp, 0, 0, 0);
            a2B = MFMA16(p1, ybB1, a2B, 0, 0, 0);

            *(uint2*)(XP2 + (size_t)nodeA * 64 + w * 16 + quad * 4) =
                (uint2){pack_relu(a2A[0], a2A[1]), pack_relu(a2A[2], a2A[3])};
            if (actB) *(uint2*)(XP2 + (size_t)nodeB * 64 + w * 16 + quad * 4) =
                (uint2){pack_relu(a2B[0], a2B[1]), pack_relu(a2B[2], a2B[3])};
            soft_barrier();   // bufY reuse guard for next rep
        }
    }
}

// ---------------------------------------------------------------------------
// lstm_post: layer-2 LSTM + fused Y2[128]->T1[192]->T2[64]->out[64] f32;
// 2 groups (64 nodes) per block
// ---------------------------------------------------------------------------
__global__ __launch_bounds__(256) void lstm_post(
    const u16* __restrict__ xp, const int* __restrict__ src,
    const u16* __restrict__ wihs, const u16* __restrict__ whhs,
    const u16* __restrict__ bih, const u16* __restrict__ bhh,
    const u16* __restrict__ Y1,
    const u16* __restrict__ llw2, const u16* __restrict__ llb2,
    const u16* __restrict__ lrw2,
    const u16* __restrict__ w1m, const u16* __restrict__ b1m,
    const u16* __restrict__ w2m, const u16* __restrict__ b2m,
    const u16* __restrict__ w3m, const u16* __restrict__ b3m,
    float* __restrict__ outp, int N)
{
    __shared__ float lds_b[256];        // 1KB
    __shared__ u16 lds_h[2][32 * 64];   // 8KB
    __shared__ u16 bufA[32 * 128];      // 8KB Y2 exchange (reused for T2 @ 64)
    __shared__ u16 bufB[32 * 192];      // 12KB T1 exchange

    LSTM_SETUP

#pragma unroll 1
    for (int rep = 0; rep < 2; ++rep) {
        const int node0 = (blockIdx.x * 2 + rep) * 32;
        if (node0 >= N) break;
        const bool actB = (node0 + 32 <= N);
        const int nodeA = node0 + col;
        const int nodeB = actB ? (node0 + 16 + col) : nodeA;

        LSTM_GROUP_INIT
        LSTM2_CORE_LOOP

        // ---- epilogue ----
        {
            const u16* yrA = Y1 + (size_t)nodeA * 64 + quad * 8;
            short8 ryA0 = *(const short8*)yrA, ryA1 = *(const short8*)(yrA + 32);
            const u16* yrB = Y1 + (size_t)nodeB * 64 + quad * 8;
            short8 ryB0 = *(const short8*)yrB, ryB1 = *(const short8*)(yrB + 32);

            // Y2 tiles jt = 2w, 2w+1
#pragma unroll
            for (int ti = 0; ti < 2; ++ti) {
                int jt = 2 * w + ti;
                const u16* wr = llw2 + (size_t)(jt * 16 + col) * 64 + quad * 8;
                short8 l0 = *(const short8*)wr, l1 = *(const short8*)(wr + 32);
                const u16* wr2 = lrw2 + (size_t)(jt * 16 + col) * 64 + quad * 8;
                short8 r0 = *(const short8*)wr2, r1 = *(const short8*)(wr2 + 32);
                f32x4 b0 = bias4(llb2 + jt * 16 + quad * 4);
                f32x4 aA = MFMA16(l0, hbA0, b0, 0, 0, 0);
                aA = MFMA16(l1, hbA1, aA, 0, 0, 0);
                aA = MFMA16(r0, ryA0, aA, 0, 0, 0);
                aA = MFMA16(r1, ryA1, aA, 0, 0, 0);
                xwrite(bufA, 128, col, quad, jt, pack_relu(aA[0], aA[1]), pack_relu(aA[2], aA[3]));
                f32x4 aB = MFMA16(l0, hbB0, b0, 0, 0, 0);
                aB = MFMA16(l1, hbB1, aB, 0, 0, 0);
                aB = MFMA16(r0, ryB0, aB, 0, 0, 0);
                aB = MFMA16(r1, ryB1, aB, 0, 0, 0);
                xwrite(bufA, 128, col + 16, quad, jt, pack_relu(aB[0], aB[1]), pack_relu(aB[2], aB[3]));
            }
            soft_barrier();

            short8 y2A[4], y2B[4];
#pragma unroll
            for (int kc = 0; kc < 4; ++kc) {
                y2A[kc] = xread(bufA, 128, col,      quad, kc);
                y2B[kc] = xread(bufA, 128, col + 16, quad, kc);
            }
            // T1 tiles jt = 3w..3w+2, K=128
#pragma unroll
            for (int ti = 0; ti < 3; ++ti) {
                int jt = 3 * w + ti;
                const u16* wr = w1m + (size_t)(jt * 16 + col) * 128 + quad * 8;
                short8 wk[4];
#pragma unroll
                for (int kc = 0; kc < 4; ++kc) wk[kc] = *(const short8*)(wr + kc * 32);
                f32x4 b1v = bias4(b1m + jt * 16 + quad * 4);
                f32x4 aA = b1v, aB = b1v;
#pragma unroll
                for (int kc = 0; kc < 4; ++kc) {
                    aA = MFMA16(wk[kc], y2A[kc], aA, 0, 0, 0);
                    aB = MFMA16(wk[kc], y2B[kc], aB, 0, 0, 0);
                }
                xwrite(bufB, 192, col,      quad, jt, pack_relu(aA[0], aA[1]), pack_relu(aA[2], aA[3]));
                xwrite(bufB, 192, col + 16, quad, jt, pack_relu(aB[0], aB[1]), pack_relu(aB[2], aB[3]));
            }
            soft_barrier();

            short8 t1A[6], t1B[6];
#pragma unroll
            for (int kc = 0; kc < 6; ++kc) {
                t1A[kc] = xread(bufB, 192, col,      quad, kc);
                t1B[kc] = xread(bufB, 192, col + 16, quad, kc);
            }
            // T2 tile jt=w, K=192 (bufA reuse @ stride 64 — Y2 reads drained at T1 barrier)
            {
                const u16* wr = w2m + (size_t)(w * 16 + col) * 192 + quad * 8;
                f32x4 b2v = bias4(b2m + w * 16 + quad * 4);
                f32x4 aA = b2v, aB = b2v;
#pragma unroll
                for (int kc = 0; kc < 6; ++kc) {
                    short8 wk = *(const short8*)(wr + kc * 32);
                    aA = MFMA16(wk, t1A[kc], aA, 0, 0, 0);
                    aB = MFMA16(wk, t1B[kc], aB, 0, 0, 0);
                }
                xwrite(bufA, 64, col,      quad, w, pack_relu(aA[0], aA[1]), pack_relu(aA[2], aA[3]));
                xwrite(bufA, 64, col + 16, quad, w, pack_relu(aB[0], aB[1]), pack_relu(aB[2], aB[3]));
            }
            soft_barrier();

            short8 t2A0 = xread(bufA, 64, col,      quad, 0);
            short8 t2A1 = xread(bufA, 64, col,      quad, 1);
            short8 t2B0 = xread(bufA, 64, col + 16, quad, 0);
            short8 t2B1 = xread(bufA, 64, col + 16, quad, 1);
            // out tile jt=w, K=64, f32 store
            {
                const u16* wr = w3m + (size_t)(w * 16 + col) * 64 + quad * 8;
                short8 l0 = *(const short8*)wr, l1 = *(const short8*)(wr + 32);
                f32x4 b3v = bias4(b3m + w * 16 + quad * 4);
                f32x4 aA = MFMA16(l0, t2A0, b3v, 0, 0, 0);
                aA = MFMA16(l1, t2A1, aA, 0, 0, 0);
                f32x4 aB = MFMA16(l0, t2B0, b3v, 0, 0, 0);
                aB = MFMA16(l1, t2B1, aB, 0, 0, 0);
                float4 oA;
                oA.x = fmaxf(aA[0], 0.f); oA.y = fmaxf(aA[1], 0.f);
                oA.z = fmaxf(aA[2], 0.f); oA.w = fmaxf(aA[3], 0.f);
                *(float4*)(outp + (size_t)nodeA * 64 + w * 16 + quad * 4) = oA;
                if (actB) {
                    float4 oB;
                    oB.x = fmaxf(aB[0], 0.f); oB.y = fmaxf(aB[1], 0.f);
                    oB.z = fmaxf(aB[2], 0.f); oB.w = fmaxf(aB[3], 0.f);
                    *(float4*)(outp + (size_t)nodeB * 64 + w * 16 + quad * 4) = oB;
                }
            }
            soft_barrier();   // buf reuse guard for next rep
        }
    }
}

// ---------------------------------------------------------------------------
extern "C" void kernel_launch(void* const* d_in, const int* in_sizes, int n_in,
                              void* d_out, int out_size, void* d_ws, size_t ws_size,
                              hipStream_t stream)
{
    const u16* x       = (const u16*)d_in[0];
    const int* edge    = (const int*)d_in[1];
    const u16* p1_pw   = (const u16*)d_in[3];
    const u16* p1_pb   = (const u16*)d_in[4];
    const u16* p1_wih  = (const u16*)d_in[5];
    const u16* p1_whh  = (const u16*)d_in[6];
    const u16* p1_bih  = (const u16*)d_in[7];
    const u16* p1_bhh  = (const u16*)d_in[8];
    const u16* p1_llw  = (const u16*)d_in[9];
    const u16* p1_llb  = (const u16*)d_in[10];
    const u16* p1_lrw  = (const u16*)d_in[11];
    const u16* p2_pw   = (const u16*)d_in[12];
    const u16* p2_pb   = (const u16*)d_in[13];
    const u16* p2_wih  = (const u16*)d_in[14];
    const u16* p2_whh  = (const u16*)d_in[15];
    const u16* p2_bih  = (const u16*)d_in[16];
    const u16* p2_bhh  = (const u16*)d_in[17];
    const u16* p2_llw  = (const u16*)d_in[18];
    const u16* p2_llb  = (const u16*)d_in[19];
    const u16* p2_lrw  = (const u16*)d_in[20];
    const u16* lin1w   = (const u16*)d_in[21];
    const u16* lin1b   = (const u16*)d_in[22];
    const u16* lin2w   = (const u16*)d_in[23];
    const u16* lin2b   = (const u16*)d_in[24];
    const u16* lin3w   = (const u16*)d_in[25];
    const u16* lin3b   = (const u16*)d_in[26];
    (void)n_in; (void)ws_size;

    const int N  = in_sizes[0] / 64;     // 50000
    const int E2 = in_sizes[1];          // 1600000
    const int* srcIdx = edge;

    // workspace: scaled weights 128KB @0; xp1 @1MB; xp2 @8MB; Y1 @15MB
    char* w = (char*)d_ws;
    u16* wss   = (u16*)(w);
    u16* xp1   = (u16*)(w + 1u  * 1024 * 1024);
    u16* xp2   = (u16*)(w + 8u  * 1024 * 1024);
    u16* bufY1 = (u16*)(w + 15u * 1024 * 1024);
    u16* wih1s = wss;
    u16* whh1s = wss + 16384;
    u16* wih2s = wss + 32768;
    u16* whh2s = wss + 49152;

    float* out_h    = (float*)d_out;
    float* out_edge = (float*)d_out + (size_t)N * 64;
    (void)out_size;

    const int tiles = (N + 63) / 64;          // 782 GEMM row-tiles
    const int gpre  = (tiles + 1) / 2;        // 391 k_pre blocks
    const int gbl   = (N + 63) / 64;          // 782 lstm blocks (64 nodes each)
    const int n4    = E2 / 4;

    dim3 block(256);

    hipLaunchKernelGGL(k_pre, dim3(gpre), block, 0, stream,
                       x, p1_pw, p1_pb, xp1, N,
                       edge, out_edge, n4,
                       p1_wih, p1_whh, p2_wih, p2_whh, wss);
    hipLaunchKernelGGL(lstm_mid, dim3(gbl), block, 0, stream,
                       xp1, srcIdx, wih1s, whh1s, p1_bih, p1_bhh,
                       x, p1_llw, p1_llb, p1_lrw, p2_pw, p2_pb, bufY1, xp2, N);
    hipLaunchKernelGGL(lstm_post, dim3(gbl), block, 0, stream,
                       xp2, srcIdx, wih2s, whh2s, p2_bih, p2_bhh,
                       bufY1, p2_llw, p2_llb, p2_lrw,
                       lin1w, lin1b, lin2w, lin2b, lin3w, lin3b, out_h, N);
}